// Round 4
// baseline (452.064 us; speedup 1.0000x reference)
//
#include <hip/hip_runtime.h>

typedef unsigned int u32;
typedef float f32x4 __attribute__((ext_vector_type(4)));

// Shapes (hardcoded from setup_inputs): B=4, C=32, Cr=16, H=64, W=128, D=48.
// Output (B, 64, D, H, W) f32 = 402.7 MB pure writes.
// channels [0,32)=cost_var=((l-r_shift)/2)^2 masked, [32,48)=cat_l, [48,64)=cat_r.
//
// Round-3 restructure: one 256-thread block per OUTPUT PLANE (b, c, d).
//   grid = 4*64*48 = 12288 blocks; each block writes one 32 KB CONTIGUOUS
//   (H,W) plane, and bid equals the plane's position in the output layout,
//   so the dispatch front sweeps the 403 MB linearly (fill-like, HBM
//   row-buffer friendly). Previous mapping scattered 512 B granules at
//   32 KB/256 KB strides -> 2.9 TB/s; harness fill proves 6.3 TB/s.
//
// d is UNIFORM per block -> no LDS needed at all: the shifted right-image
// reads are lane-consecutive scalar dword loads (perfectly coalesced,
// L2-resident planes, reused by the 48 d-blocks of the same channel).
// Per thread: 8 iterations; iteration it covers flat = it*1024 + tid*4,
// i.e. each wave store instruction writes 1 KB contiguous.
__global__ __launch_bounds__(256) void costvol_kernel(
    const float* __restrict__ left, const float* __restrict__ rleft,
    const float* __restrict__ right, const float* __restrict__ rright,
    float* __restrict__ out)
{
    const u32 bid = blockIdx.x;          // ((b*64 + c)*48 + d)
    const u32 d = bid % 48u;             // uniform per block (SGPR)
    const u32 t = bid / 48u;             // b*64 + c
    const u32 c = t & 63u;
    const u32 b = t >> 6;
    const u32 tid = threadIdx.x;

    float* oplane = out + (size_t)bid * 8192u;   // 32 KB contiguous target

    if (c < 32u) {
        // ---- cost_var channel c: ((l[w] - r[w-d]) / 2)^2, masked by w>=d ----
        const float* lp = left  + (size_t)(b * 32u + c) * 8192u;
        const float* rp = right + (size_t)(b * 32u + c) * 8192u;
        #pragma unroll
        for (u32 it = 0; it < 8u; ++it) {
            const u32 flat = it * 1024u + tid * 4u;
            const u32 w0 = flat & 127u;
            const f32x4 l4 = *(const f32x4*)(lp + flat);
            float o[4];
            #pragma unroll
            for (int j = 0; j < 4; ++j) {
                const u32 w = w0 + (u32)j;
                const bool act = (w >= d);
                // when act: flat+j-d = h*128 + (w-d) >= 0 and stays in-row
                const u32 ri = act ? (flat + (u32)j - d) : 0u;
                const float r = rp[ri];
                const float tv = (l4[j] - r) * 0.5f;
                o[j] = act ? (tv * tv) : 0.0f;
            }
            f32x4 ov = { o[0], o[1], o[2], o[3] };
            __builtin_nontemporal_store(ov, (f32x4*)(oplane + flat));
        }
    } else if (c < 48u) {
        // ---- cat_l channel c-32: masked copy (no shift) ----
        const float* sp = rleft + (size_t)(b * 16u + (c - 32u)) * 8192u;
        #pragma unroll
        for (u32 it = 0; it < 8u; ++it) {
            const u32 flat = it * 1024u + tid * 4u;
            const u32 w0 = flat & 127u;
            const f32x4 v = *(const f32x4*)(sp + flat);
            f32x4 ov = { (w0      >= d) ? v[0] : 0.0f,
                         (w0 + 1u >= d) ? v[1] : 0.0f,
                         (w0 + 2u >= d) ? v[2] : 0.0f,
                         (w0 + 3u >= d) ? v[3] : 0.0f };
            __builtin_nontemporal_store(ov, (f32x4*)(oplane + flat));
        }
    } else {
        // ---- cat_r channel c-48: shifted masked copy ----
        const float* sp = rright + (size_t)(b * 16u + (c - 48u)) * 8192u;
        #pragma unroll
        for (u32 it = 0; it < 8u; ++it) {
            const u32 flat = it * 1024u + tid * 4u;
            const u32 w0 = flat & 127u;
            float o[4];
            #pragma unroll
            for (int j = 0; j < 4; ++j) {
                const u32 w = w0 + (u32)j;
                const bool act = (w >= d);
                const u32 ri = act ? (flat + (u32)j - d) : 0u;
                o[j] = act ? sp[ri] : 0.0f;
            }
            f32x4 ov = { o[0], o[1], o[2], o[3] };
            __builtin_nontemporal_store(ov, (f32x4*)(oplane + flat));
        }
    }
}

extern "C" void kernel_launch(void* const* d_in, const int* in_sizes, int n_in,
                              void* d_out, int out_size, void* d_ws, size_t ws_size,
                              hipStream_t stream) {
    const float* left   = (const float*)d_in[0];
    const float* rleft  = (const float*)d_in[1];
    const float* right  = (const float*)d_in[2];
    const float* rright = (const float*)d_in[3];
    float* out = (float*)d_out;
    // one block per output plane (b, c, d): 4 * 64 * 48 = 12288 blocks
    const u32 blocks = 4u * 64u * 48u;
    costvol_kernel<<<blocks, 256, 0, stream>>>(left, rleft, right, rright, out);
}

// Round 5
// 428.133 us; speedup vs baseline: 1.0559x; 1.0559x over previous
//
#include <hip/hip_runtime.h>

typedef unsigned int u32;
typedef float f32x4 __attribute__((ext_vector_type(4)));

// Shapes (hardcoded from setup_inputs): B=4, C=32, Cr=16, H=64, W=128, D=48.
// Output (B, 64, D, H, W) f32 = 402.7 MB pure writes.
// channels [0,32)=cost_var=((l-r_shift)/2)^2 masked, [32,48)=cat_l, [48,64)=cat_r.
//
// Round-5: plane-per-block (R4 structure) + LDS-staged shifted reads (R3 read
// path). R4 showed write contiguity is NOT the lever (regressed vs R3); its
// regression was the 4x scalar 16B-lane-strided global loads for r[w-d]
// (64 cache-line segments per instruction, 4x instruction count). Fix: stage
// the 32 KB source plane in LDS once per block, read the d-shift from LDS.
//
// One 256-thread block per output plane (b, c, d): grid = 12288, bid equals
// the plane's position in the output layout (linear sweep of the 403 MB).
// d is uniform per block -> masks are half-uniform, no per-thread d decode.
//
// LDS swizzle: value idx lives at srow[idx + (idx>>5)] (8448 floats, 33.8 KB).
// Shift-read lane stride is 4 floats (8-way bank alias); the +(idx>>5)
// stagger makes it 2-way across 64 lanes = free (learn_hip m136).
// Swizzled addresses are only 4 B aligned -> staging uses scalar ds writes.
__global__ __launch_bounds__(256) void costvol_kernel(
    const float* __restrict__ left, const float* __restrict__ rleft,
    const float* __restrict__ right, const float* __restrict__ rright,
    float* __restrict__ out)
{
    const u32 bid = blockIdx.x;          // ((b*64 + c)*48 + d)
    const u32 d = bid % 48u;             // uniform per block
    const u32 t = bid / 48u;             // b*64 + c
    const u32 c = t & 63u;
    const u32 b = t >> 6;
    const u32 tid = threadIdx.x;

    __shared__ float srow[8448];         // swizzled plane

    float* oplane = out + (size_t)bid * 8192u;   // 32 KB contiguous target

    if (c < 32u) {
        // ---- cost_var channel c: ((l[w] - r[w-d]) / 2)^2, masked by w>=d ----
        const float* lp = left  + (size_t)(b * 32u + c) * 8192u;
        const float* rp = right + (size_t)(b * 32u + c) * 8192u;

        #pragma unroll
        for (u32 s = 0; s < 8u; ++s) {   // stage right plane -> LDS (swizzled)
            const u32 idx = s * 1024u + tid * 4u;      // 1 KB/wave, coalesced
            const f32x4 v = *(const f32x4*)(rp + idx);
            const u32 sw = idx + (idx >> 5);
            srow[sw]      = v[0];
            srow[sw + 1u] = v[1];
            srow[sw + 2u] = v[2];
            srow[sw + 3u] = v[3];
        }
        __syncthreads();

        #pragma unroll
        for (u32 it = 0; it < 8u; ++it) {
            const u32 flat = it * 1024u + tid * 4u;
            const u32 w0 = flat & 127u;
            const f32x4 l4 = *(const f32x4*)(lp + flat);
            float o[4];
            #pragma unroll
            for (int j = 0; j < 4; ++j) {
                const u32 w = w0 + (u32)j;
                const bool act = (w >= d);
                const u32 ri = act ? (flat + (u32)j - d) : 0u;  // in-plane
                const float r = srow[ri + (ri >> 5)];
                const float tv = (l4[j] - r) * 0.5f;
                o[j] = act ? (tv * tv) : 0.0f;
            }
            f32x4 ov = { o[0], o[1], o[2], o[3] };
            __builtin_nontemporal_store(ov, (f32x4*)(oplane + flat));
        }
    } else if (c < 48u) {
        // ---- cat_l channel c-32: masked copy (no shift, no LDS) ----
        const float* sp = rleft + (size_t)(b * 16u + (c - 32u)) * 8192u;
        #pragma unroll
        for (u32 it = 0; it < 8u; ++it) {
            const u32 flat = it * 1024u + tid * 4u;
            const u32 w0 = flat & 127u;
            const f32x4 v = *(const f32x4*)(sp + flat);
            f32x4 ov = { (w0      >= d) ? v[0] : 0.0f,
                         (w0 + 1u >= d) ? v[1] : 0.0f,
                         (w0 + 2u >= d) ? v[2] : 0.0f,
                         (w0 + 3u >= d) ? v[3] : 0.0f };
            __builtin_nontemporal_store(ov, (f32x4*)(oplane + flat));
        }
    } else {
        // ---- cat_r channel c-48: shifted masked copy via LDS ----
        const float* sp = rright + (size_t)(b * 16u + (c - 48u)) * 8192u;

        #pragma unroll
        for (u32 s = 0; s < 8u; ++s) {   // stage plane -> LDS (swizzled)
            const u32 idx = s * 1024u + tid * 4u;
            const f32x4 v = *(const f32x4*)(sp + idx);
            const u32 sw = idx + (idx >> 5);
            srow[sw]      = v[0];
            srow[sw + 1u] = v[1];
            srow[sw + 2u] = v[2];
            srow[sw + 3u] = v[3];
        }
        __syncthreads();

        #pragma unroll
        for (u32 it = 0; it < 8u; ++it) {
            const u32 flat = it * 1024u + tid * 4u;
            const u32 w0 = flat & 127u;
            float o[4];
            #pragma unroll
            for (int j = 0; j < 4; ++j) {
                const u32 w = w0 + (u32)j;
                const bool act = (w >= d);
                const u32 ri = act ? (flat + (u32)j - d) : 0u;
                o[j] = act ? srow[ri + (ri >> 5)] : 0.0f;
            }
            f32x4 ov = { o[0], o[1], o[2], o[3] };
            __builtin_nontemporal_store(ov, (f32x4*)(oplane + flat));
        }
    }
}

extern "C" void kernel_launch(void* const* d_in, const int* in_sizes, int n_in,
                              void* d_out, int out_size, void* d_ws, size_t ws_size,
                              hipStream_t stream) {
    const float* left   = (const float*)d_in[0];
    const float* rleft  = (const float*)d_in[1];
    const float* right  = (const float*)d_in[2];
    const float* rright = (const float*)d_in[3];
    float* out = (float*)d_out;
    // one block per output plane (b, c, d): 4 * 64 * 48 = 12288 blocks
    const u32 blocks = 4u * 64u * 48u;
    costvol_kernel<<<blocks, 256, 0, stream>>>(left, rleft, right, rright, out);
}

// Round 6
// 401.593 us; speedup vs baseline: 1.1257x; 1.0661x over previous
//
#include <hip/hip_runtime.h>

typedef unsigned int u32;
typedef float f32x4 __attribute__((ext_vector_type(4)));

// Shapes (hardcoded from setup_inputs): B=4, C=32, Cr=16, H=64, W=128, D=48.
// Output (B, 64, D, H, W) f32 = 402.7 MB pure writes.
// channels [0,32)=cost_var=((l-r_shift)/2)^2 masked, [32,48)=cat_l, [48,64)=cat_r.
//
// Round-6: block = (b, c, hc) where hc indexes an 8-row chunk of H.
//   grid = 4*64*8 = 2048 blocks, 256 threads.
//   Thread t owns the f32x4 at chunk-local flat position 4t (row t>>5,
//   col (t&31)*4) -- FIXED across d. Loop d=0..47 (uniform/scalar):
//   one f32x4 store per thread per d; each wave stores 1 KB contiguous.
//
// Combines the winners of R3/R4/R5:
//   - staging amortized 48x (R3): stage the 4 KB source chunk in LDS once,
//     emit 192 KB of output from it; inputs read exactly once chip-wide.
//   - uniform d + contiguous plane stores (R4/R5): no per-thread d decode,
//     scalar mask half, linear-ish sweep of the output.
//   - tiny LDS (4.2 KB) + ~32 VGPR -> high occupancy (vs R5's 4 blocks/CU).
//   - plain (non-nt) stores: the 6.3 TB/s harness fill uses plain stores;
//     write-allocate adds no HBM bytes for a full-line stream.
//
// LDS swizzle: value idx lives at srow[idx + (idx>>5)] (1056 floats).
// d-shift read lane-stride is 4 floats (8-way bank alias unswizzled);
// the +(idx>>5) stagger makes it ~2-way = free (learn_hip m136).
__global__ __launch_bounds__(256) void costvol_kernel(
    const float* __restrict__ left, const float* __restrict__ rleft,
    const float* __restrict__ right, const float* __restrict__ rright,
    float* __restrict__ out)
{
    const u32 bid = blockIdx.x;          // (b*64 + c)*8 + hc
    const u32 hc = bid & 7u;             // 8-row chunk index
    const u32 t  = bid >> 3;             // b*64 + c
    const u32 c  = t & 63u;
    const u32 b  = t >> 6;
    const u32 tid = threadIdx.x;

    __shared__ float srow[1056];         // swizzled 8-row source chunk

    const u32 flat = tid * 4u;           // chunk-local float offset (0..1020)
    const u32 w0 = flat & 127u;          // col of elem 0

    // output base for this thread at d=0: ((b*64+c)*48 + 0)*8192 + hc*1024 + flat
    float* obase = out + (size_t)t * 48u * 8192u + hc * 1024u + flat;

    if (c < 32u) {
        // ---- cost_var channel c: ((l[w] - r[w-d]) / 2)^2, masked by w>=d ----
        const float* lp = left  + (size_t)(b * 32u + c) * 8192u + hc * 1024u;
        const float* rp = right + (size_t)(b * 32u + c) * 8192u + hc * 1024u;

        { // stage 4 KB source chunk -> LDS (swizzled); one f32x4 per thread
            const f32x4 v = *(const f32x4*)(rp + flat);
            const u32 sw = flat + (flat >> 5);   // flat..flat+3 same 32-block
            srow[sw]      = v[0];
            srow[sw + 1u] = v[1];
            srow[sw + 2u] = v[2];
            srow[sw + 3u] = v[3];
        }
        const f32x4 l4 = *(const f32x4*)(lp + flat);   // register-resident, reused 48x
        __syncthreads();

        #pragma unroll 8
        for (u32 d = 0; d < 48u; ++d) {
            float o[4];
            #pragma unroll
            for (int j = 0; j < 4; ++j) {
                const u32 w = w0 + (u32)j;
                const bool act = (w >= d);
                const u32 ri = act ? (flat + (u32)j - d) : 0u;  // stays in-row
                const float r = srow[ri + (ri >> 5)];
                const float tv = (l4[j] - r) * 0.5f;
                o[j] = act ? (tv * tv) : 0.0f;
            }
            f32x4 ov = { o[0], o[1], o[2], o[3] };
            *(f32x4*)(obase + d * 8192u) = ov;
        }
    } else if (c < 48u) {
        // ---- cat_l channel c-32: masked copy (no shift, no LDS) ----
        const float* sp = rleft + (size_t)(b * 16u + (c - 32u)) * 8192u + hc * 1024u;
        const f32x4 v = *(const f32x4*)(sp + flat);

        #pragma unroll 8
        for (u32 d = 0; d < 48u; ++d) {
            f32x4 ov = { (w0      >= d) ? v[0] : 0.0f,
                         (w0 + 1u >= d) ? v[1] : 0.0f,
                         (w0 + 2u >= d) ? v[2] : 0.0f,
                         (w0 + 3u >= d) ? v[3] : 0.0f };
            *(f32x4*)(obase + d * 8192u) = ov;
        }
    } else {
        // ---- cat_r channel c-48: shifted masked copy via LDS ----
        const float* sp = rright + (size_t)(b * 16u + (c - 48u)) * 8192u + hc * 1024u;

        {
            const f32x4 v = *(const f32x4*)(sp + flat);
            const u32 sw = flat + (flat >> 5);
            srow[sw]      = v[0];
            srow[sw + 1u] = v[1];
            srow[sw + 2u] = v[2];
            srow[sw + 3u] = v[3];
        }
        __syncthreads();

        #pragma unroll 8
        for (u32 d = 0; d < 48u; ++d) {
            float o[4];
            #pragma unroll
            for (int j = 0; j < 4; ++j) {
                const u32 w = w0 + (u32)j;
                const bool act = (w >= d);
                const u32 ri = act ? (flat + (u32)j - d) : 0u;
                o[j] = act ? srow[ri + (ri >> 5)] : 0.0f;
            }
            f32x4 ov = { o[0], o[1], o[2], o[3] };
            *(f32x4*)(obase + d * 8192u) = ov;
        }
    }
}

extern "C" void kernel_launch(void* const* d_in, const int* in_sizes, int n_in,
                              void* d_out, int out_size, void* d_ws, size_t ws_size,
                              hipStream_t stream) {
    const float* left   = (const float*)d_in[0];
    const float* rleft  = (const float*)d_in[1];
    const float* right  = (const float*)d_in[2];
    const float* rright = (const float*)d_in[3];
    float* out = (float*)d_out;
    // one block per (b, c, 8-row chunk): 4 * 64 * 8 = 2048 blocks
    const u32 blocks = 4u * 64u * 8u;
    costvol_kernel<<<blocks, 256, 0, stream>>>(left, rleft, right, rright, out);
}